// Round 5
// baseline (395.906 us; speedup 1.0000x reference)
//
#include <hip/hip_runtime.h>

#define CI    32
#define IH    224
#define IW    224
#define OHS   220
#define OWS   220
#define NF    64
#define KS    5

// fallback-kernel macros
#define XCOLS 228
#define CP    36
#define WPD   40
#define XROWS 8
#define NBUFW (KS * NF * WPD)

// conv_full staged tile: 8 rows x 228 px x 32 c bf16, flat 16B chunks
#define RCHKF 912                // 16B chunks per staged row (228 px * 4)
#define ROWBF (RCHKF * 16)       // 14592 B per staged row
#define SROWSF 8
#define TCHKF (RCHKF * SROWSF)   // 7296 chunks = 114 wave-groups of 64

typedef __attribute__((ext_vector_type(4))) float   f32x4;
typedef __attribute__((ext_vector_type(4))) __bf16  bf16x4;
typedef __attribute__((ext_vector_type(8))) __bf16  bf16x8;

// Fused prep: x fp32 NCHW -> bf16 NHWC, plus (blocks 0..199) weight repack
// fp32 [f][c][kh][kw] -> bf16 [tap][f][c].
__global__ __launch_bounds__(256)
void prep_kernel(const float* __restrict__ x, const float* __restrict__ w,
                 __bf16* __restrict__ xh, __bf16* __restrict__ wp) {
  int chunk = blockIdx.x * 256 + threadIdx.x;   // 16*224*224*4 chunks of 8 channels
  int c8  = (chunk & 3) * 8;
  int pos = chunk >> 2;                         // n*50176 + h*224 + w
  int ww  = pos % IW;
  int nh  = pos / IW;
  int n   = nh / IH;
  int h   = nh - n * IH;
  const float* xp = x + ((size_t)n * CI + c8) * (IH * IW) + h * IW + ww;
  bf16x8 v;
#pragma unroll
  for (int j = 0; j < 8; ++j) v[j] = (__bf16)xp[(size_t)j * (IH * IW)];
  *(bf16x8*)(xh + (size_t)pos * CI + c8) = v;

  if (blockIdx.x < 200) {                       // 200*256 == 51200 exactly
    int i = blockIdx.x * 256 + threadIdx.x;
    int c   = i & (CI - 1);
    int f   = (i >> 5) & (NF - 1);
    int tap = i >> 11;
    int kh = tap / KS, kw = tap % KS;
    wp[i] = (__bf16)w[((f * CI + c) * KS + kh) * KS + kw];
  }
}

// Full-width LDS-staged conv: block = 512 thr (8 waves) = 4 output rows x full
// 220 ow x 64 f. Staged 8 rows x 228 px (116.7KB), one barrier, weights direct
// from global. Full-row output writes -> no partial-cache-line RFO penalty.
__global__ __launch_bounds__(512, 2)
void conv_full(const __bf16* __restrict__ xh, const __bf16* __restrict__ wp,
               const float* __restrict__ bias, float* __restrict__ out) {
  __shared__ __bf16 xs[TCHKF * 8];   // 116736 B

  const int tid  = threadIdx.x;
  const int lane = tid & 63;
  const int wv   = tid >> 6;    // 0..7
  const int m    = lane & 15;   // MFMA col (pixel) / A row (filter)
  const int q    = lane >> 4;   // c-chunk / C row group

  const int bid = blockIdx.x;
  const int lid = (bid & 7) * 110 + (bid >> 3);  // bijection on [0,880), 880=8*110
  const int n   = lid / 55;
  const int oh0 = (lid - n * 55) * 4;            // 0,4,...,216

  // ---- stage rows oh0..oh0+7, px 0..227 (last 4 px = next-row spill, feeds
  // only masked ow>=220 outputs; max read ends 256B past xh, inside wp) ----
  {
    const __bf16* xb = xh + (size_t)(n * IH + oh0) * (IW * CI);
    for (int g = wv; g < TCHKF / 64; g += 8) {   // 114 wave-uniform groups
      int L = g * 64 + lane;
      int r = L / RCHKF;          // staged row 0..7
      int c = L - r * RCHKF;      // chunk within row 0..911
      __builtin_amdgcn_global_load_lds(
          (const __attribute__((address_space(1))) void*)(xb + (size_t)r * (IW * CI) + c * 8),
          (__attribute__((address_space(3))) void*)&xs[g * 512], 16, 0, 0);
    }
  }

  // per-wave tiles: t = wv + 8j over 56 = 4 rows x 14 col-tiles (7 per wave)
  int cbj[7], rjv[7], bbase[7];
#pragma unroll
  for (int j = 0; j < 7; ++j) {
    int t  = wv + j * 8;          // 0..55
    int rj = t / 14;              // output row offset 0..3
    rjv[j] = rj;
    cbj[j] = (t % 14) * 16;       // 0..208
    bbase[j] = rj * ROWBF + (cbj[j] + m) * 64 + q * 16;   // byte offset kh=kw=0
  }

  f32x4 acc[28];
#pragma unroll
  for (int i = 0; i < 28; ++i) { f32x4 z = {0.f, 0.f, 0.f, 0.f}; acc[i] = z; }

  const __bf16* wpl = wp + m * CI + q * 8;    // lane base into [tap][f][c]

  __syncthreads();

  for (int kh = 0; kh < KS; ++kh) {
    const int khb = kh * ROWBF;
#pragma unroll
    for (int kw = 0; kw < KS; ++kw) {
      bf16x8 af[4];
#pragma unroll
      for (int ft = 0; ft < 4; ++ft)          // 1KB/wave coalesced, L1/L2-resident
        af[ft] = *(const bf16x8*)(wpl + (size_t)(kh * KS + kw) * (NF * CI) + ft * 16 * CI);
#pragma unroll
      for (int j = 0; j < 7; ++j) {
        bf16x8 bv = *(const bf16x8*)((const char*)xs + khb + bbase[j] + kw * 64);
#pragma unroll
        for (int ft = 0; ft < 4; ++ft)
          acc[j * 4 + ft] =
              __builtin_amdgcn_mfma_f32_16x16x32_bf16(af[ft], bv, acc[j * 4 + ft], 0, 0, 0);
      }
    }
  }

  // epilogue: C/D layout col=lane&15 (pixel), row=q*4+reg (filter within 16)
  float bvv[16];
#pragma unroll
  for (int ft = 0; ft < 4; ++ft)
#pragma unroll
    for (int rg = 0; rg < 4; ++rg)
      bvv[ft * 4 + rg] = bias[ft * 16 + q * 4 + rg];

#pragma unroll
  for (int j = 0; j < 7; ++j) {
    int ow = cbj[j] + m;
    if (ow < OWS) {               // only tile 13 masks (px 220..223)
      int oh = oh0 + rjv[j];
#pragma unroll
      for (int ft = 0; ft < 4; ++ft)
#pragma unroll
        for (int rg = 0; rg < 4; ++rg) {
          int f = ft * 16 + q * 4 + rg;
          out[(((size_t)n * NF + f) * OHS + oh) * OWS + ow] =
              acc[j * 4 + ft][rg] + bvv[ft * 4 + rg];
        }
    }
  }
}

// ---------------- fallbacks (used only if ws too small) ----
__global__ void repack_w_kernel(const float* __restrict__ w, __bf16* __restrict__ wp) {
  int i = blockIdx.x * 256 + threadIdx.x;
  if (i >= KS * KS * NF * CI) return;
  int c   = i & (CI - 1);
  int f   = (i >> 5) & (NF - 1);
  int tap = i >> 11;
  int kh = tap / KS, kw = tap % KS;
  wp[i] = (__bf16)w[((f * CI + c) * KS + kh) * KS + kw];
}

template <bool USE_WS>
__global__ __launch_bounds__(512, 1)
void conv_main(const float* __restrict__ x, const float* __restrict__ w,
               const __bf16* __restrict__ wp, const float* __restrict__ bias,
               float* __restrict__ out) {
  __shared__ __bf16 xs[XROWS * XCOLS * CP];
  __shared__ __bf16 wsm[NBUFW];

  const int tid  = threadIdx.x;
  const int lane = tid & 63;
  const int wv   = tid >> 6;
  const int m    = lane & 15;
  const int q    = lane >> 4;

  int bid = blockIdx.x;
  int lid = (bid >> 3) + (bid & 7) * 110;
  const int n   = lid / 55;
  const int oh0 = (lid % 55) * 4;

  {
    const float* xn = x + (size_t)n * CI * IH * IW;
    for (int p = tid; p < XROWS * 56 * 8; p += 512) {
      int pc   = p & 7;
      int pg   = p >> 3;
      int pcol = pg % 56;
      int prow = pg / 56;
      int row  = oh0 + prow;
      f32x4 v0 = *(const f32x4*)(xn + ((size_t)(pc * 4 + 0) * IH + row) * IW + pcol * 4);
      f32x4 v1 = *(const f32x4*)(xn + ((size_t)(pc * 4 + 1) * IH + row) * IW + pcol * 4);
      f32x4 v2 = *(const f32x4*)(xn + ((size_t)(pc * 4 + 2) * IH + row) * IW + pcol * 4);
      f32x4 v3 = *(const f32x4*)(xn + ((size_t)(pc * 4 + 3) * IH + row) * IW + pcol * 4);
#pragma unroll
      for (int dcol = 0; dcol < 4; ++dcol) {
        bf16x4 t;
        t[0] = (__bf16)v0[dcol]; t[1] = (__bf16)v1[dcol];
        t[2] = (__bf16)v2[dcol]; t[3] = (__bf16)v3[dcol];
        *(bf16x4*)&xs[(prow * XCOLS + pcol * 4 + dcol) * CP + pc * 4] = t;
      }
    }
    for (int z = tid; z < XROWS * 4 * CP; z += 512) {
      int rr  = z / (4 * CP);
      int rem = z - rr * (4 * CP);
      xs[(rr * XCOLS + 224) * CP + rem] = (__bf16)0.0f;
    }
  }

  if (USE_WS) {
    for (int i = tid; i < NF * CI * KS / 8; i += 512) {
      int c0 = (i & 3) * 8;
      int f  = (i >> 2) & 63;
      int kw = i >> 8;
      bf16x8 v = *(const bf16x8*)(wp + ((size_t)(0 * KS + kw) * NF + f) * CI + c0);
      *(bf16x8*)&wsm[(kw * NF + f) * WPD + c0] = v;
    }
  } else {
    for (int i = tid; i < KS * NF * CI; i += 512) {
      int c  = i & 31;
      int f  = (i >> 5) & 63;
      int kw = i >> 11;
      wsm[(kw * NF + f) * WPD + c] = (__bf16)w[((f * CI + c) * KS + 0) * KS + kw];
    }
  }
  __syncthreads();

  int rj[7], cbj[7], xoff[7];
#pragma unroll
  for (int j = 0; j < 7; ++j) {
    int t   = wv + j * 8;
    rj[j]   = t / 14;
    cbj[j]  = (t % 14) * 16;
    xoff[j] = (rj[j] * XCOLS + cbj[j] + m) * CP + q * 8;
  }

  f32x4 acc[28];
#pragma unroll
  for (int i = 0; i < 28; ++i) { f32x4 z = {0.f, 0.f, 0.f, 0.f}; acc[i] = z; }

  for (int kh = 0; kh < KS; ++kh) {
    bf16x8 pw[3];
    if (USE_WS && kh < KS - 1) {
#pragma unroll
      for (int it = 0; it < 3; ++it) {
        int e = it * 512 + tid;
        if (e < 1280) {
          int c0 = (e & 3) * 8;
          int f  = (e >> 2) & 63;
          int kw = e >> 8;
          pw[it] = *(const bf16x8*)(wp + ((size_t)((kh + 1) * KS + kw) * NF + f) * CI + c0);
        }
      }
    }

#pragma unroll
    for (int kw = 0; kw < KS; ++kw) {
      bf16x8 af[4];
#pragma unroll
      for (int ft = 0; ft < 4; ++ft)
        af[ft] = *(const bf16x8*)&wsm[(kw * NF + ft * 16 + m) * WPD + q * 8];
#pragma unroll
      for (int j = 0; j < 7; ++j) {
        const __bf16* bp = &xs[xoff[j] + (kh * XCOLS + kw) * CP];
        bf16x4 lo = *(const bf16x4*)bp;
        bf16x4 hi = *(const bf16x4*)(bp + 4);
        bf16x8 bv8 = __builtin_shufflevector(lo, hi, 0, 1, 2, 3, 4, 5, 6, 7);
#pragma unroll
        for (int ft = 0; ft < 4; ++ft)
          acc[j * 4 + ft] =
              __builtin_amdgcn_mfma_f32_16x16x32_bf16(af[ft], bv8, acc[j * 4 + ft], 0, 0, 0);
      }
    }

    if (kh < KS - 1) {
      __syncthreads();
      if (USE_WS) {
#pragma unroll
        for (int it = 0; it < 3; ++it) {
          int e = it * 512 + tid;
          if (e < 1280) {
            int c0 = (e & 3) * 8;
            int f  = (e >> 2) & 63;
            int kw = e >> 8;
            *(bf16x8*)&wsm[(kw * NF + f) * WPD + c0] = pw[it];
          }
        }
      } else {
        for (int i = tid; i < KS * NF * CI; i += 512) {
          int c  = i & 31;
          int f  = (i >> 5) & 63;
          int kw = i >> 11;
          wsm[(kw * NF + f) * WPD + c] =
              (__bf16)w[((f * CI + c) * KS + (kh + 1)) * KS + kw];
        }
      }
      __syncthreads();
    }
  }

  float bvv[16];
#pragma unroll
  for (int ft = 0; ft < 4; ++ft)
#pragma unroll
    for (int rg = 0; rg < 4; ++rg)
      bvv[ft * 4 + rg] = bias[ft * 16 + q * 4 + rg];

#pragma unroll
  for (int j = 0; j < 7; ++j) {
    int ow = cbj[j] + m;
    if (ow < OWS) {
      int oh = oh0 + rj[j];
#pragma unroll
      for (int ft = 0; ft < 4; ++ft) {
#pragma unroll
        for (int rg = 0; rg < 4; ++rg) {
          int f = ft * 16 + q * 4 + rg;
          out[(((size_t)n * NF + f) * OHS + oh) * OWS + ow] = acc[j * 4 + ft][rg] + bvv[ft * 4 + rg];
        }
      }
    }
  }
}

extern "C" void kernel_launch(void* const* d_in, const int* in_sizes, int n_in,
                              void* d_out, int out_size, void* d_ws, size_t ws_size,
                              hipStream_t stream) {
  const float* x    = (const float*)d_in[0];
  const float* w    = (const float*)d_in[1];
  const float* bias = (const float*)d_in[2];
  float* out = (float*)d_out;

  const int    NW = KS * KS * NF * CI;                              // 51200
  const size_t WB = (size_t)NW * sizeof(__bf16);                    // 102400 B
  const size_t XB = (size_t)16 * IH * IW * CI * sizeof(__bf16);     // 51,380,224 B

  if (ws_size >= XB + WB) {
    // fast path: NHWC bf16 x first, repacked weights after it
    __bf16* xhp = (__bf16*)d_ws;
    __bf16* wp  = (__bf16*)((char*)d_ws + XB);
    prep_kernel<<<(16 * IH * IW * 4) / 256, 256, 0, stream>>>(x, w, xhp, wp);
    conv_full<<<880, 512, 0, stream>>>(xhp, wp, bias, out);
  } else if (ws_size >= WB) {
    __bf16* wp = (__bf16*)d_ws;
    repack_w_kernel<<<(NW + 255) / 256, 256, 0, stream>>>(w, wp);
    conv_main<true><<<880, 512, 0, stream>>>(x, w, wp, bias, out);
  } else {
    conv_main<false><<<880, 512, 0, stream>>>(x, w, nullptr, bias, out);
  }
}

// Round 7
// 382.990 us; speedup vs baseline: 1.0337x; 1.0337x over previous
//
#include <hip/hip_runtime.h>

#define CI    32
#define IH    224
#define IW    224
#define OHS   220
#define OWS   220
#define NF    64
#define KS    5

// fallback-kernel macros
#define XCOLS 228
#define CP    36
#define WPD   40
#define XROWS 8
#define NBUFW (KS * NF * WPD)

// conv_ring2: staged row = 228 px x 32 c bf16 = 912 16B-chunks = 14592 B
#define RCHKR 912
#define ROWBR (RCHKR * 16)       // 14592 B
#define ROWER (RCHKR * 8)        // 7296 bf16 elems per row
#define NSLOT 3                  // ring slots -> LDS 43776 B -> 3 blocks/CU

typedef __attribute__((ext_vector_type(4))) float   f32x4;
typedef __attribute__((ext_vector_type(4))) __bf16  bf16x4;
typedef __attribute__((ext_vector_type(8))) __bf16  bf16x8;

// Fused prep: x fp32 NCHW -> bf16 NHWC, plus (blocks 0..199) weight repack
// fp32 [f][c][kh][kw] -> bf16 [tap][f][c].
__global__ __launch_bounds__(256)
void prep_kernel(const float* __restrict__ x, const float* __restrict__ w,
                 __bf16* __restrict__ xh, __bf16* __restrict__ wp) {
  int chunk = blockIdx.x * 256 + threadIdx.x;   // 16*224*224*4 chunks of 8 channels
  int c8  = (chunk & 3) * 8;
  int pos = chunk >> 2;                         // n*50176 + h*224 + w
  int ww  = pos % IW;
  int nh  = pos / IW;
  int n   = nh / IH;
  int h   = nh - n * IH;
  const float* xp = x + ((size_t)n * CI + c8) * (IH * IW) + h * IW + ww;
  bf16x8 v;
#pragma unroll
  for (int j = 0; j < 8; ++j) v[j] = (__bf16)xp[(size_t)j * (IH * IW)];
  *(bf16x8*)(xh + (size_t)pos * CI + c8) = v;

  if (blockIdx.x < 200) {                       // 200*256 == 51200 exactly
    int i = blockIdx.x * 256 + threadIdx.x;
    int c   = i & (CI - 1);
    int f   = (i >> 5) & (NF - 1);
    int tap = i >> 11;
    int kh = tap / KS, kw = tap % KS;
    wp[i] = (__bf16)w[((f * CI + c) * KS + kh) * KS + kw];
  }
}

// Stage one NHWC row (912 16B chunks) into an LDS slot. Waves 0-3 split
// groups 4/4/3/3 + 16-chunk tail on wave 3. Wave-uniform LDS base + lane*16.
__device__ __forceinline__ void stage_row(const __bf16* __restrict__ src,
                                          __bf16* dst, int wv, int lane) {
#pragma unroll
  for (int g = 0; g < 14; ++g) {
    if ((g & 3) == wv)
      __builtin_amdgcn_global_load_lds(
          (const __attribute__((address_space(1))) void*)(src + g * 512 + lane * 8),
          (__attribute__((address_space(3))) void*)(dst + g * 512), 16, 0, 0);
  }
  if (wv == 3 && lane < 16)
    __builtin_amdgcn_global_load_lds(
        (const __attribute__((address_space(1))) void*)(src + 14 * 512 + lane * 8),
        (__attribute__((address_space(3))) void*)(dst + 14 * 512), 16, 0, 0);
}

// Ring-buffer conv: block = 256 thr (4 waves) = 2 output rows x full 220 ow
// x 64 f (28 tiles, 7/wave balanced; full-row writes -> clean WRITE_SIZE).
// 3-slot LDS row ring (43.8KB) -> 3 blocks/CU; weights direct from global.
// Ring invariant: row r lives in slot r%3. Step kh reads rows {kh, kh+1};
// free slot is (kh+2)%3 (last read at kh-1) -> stage row kh+2 there (kh<=3).
// The __syncthreads at top of step kh (full vmcnt drain) orders both the
// recycled-slot readers and the landing of the row staged at kh-1.
__global__ __launch_bounds__(256, 3)
void conv_ring2(const __bf16* __restrict__ xh, const __bf16* __restrict__ wp,
                const float* __restrict__ bias, float* __restrict__ out) {
  __shared__ __bf16 xs[NSLOT * ROWER];   // 43776 B

  const int tid  = threadIdx.x;
  const int lane = tid & 63;
  const int wv   = tid >> 6;    // 0..3
  const int m    = lane & 15;   // MFMA col (pixel) / A row (filter)
  const int q    = lane >> 4;   // c-chunk / C row group

  const int bid = blockIdx.x;
  const int lid = (bid & 7) * 220 + (bid >> 3);  // bijection on [0,1760), 1760=8*220
  const int n   = lid / 110;
  const int oh0 = (lid - n * 110) * 2;           // 0,2,...,218

  const __bf16* xb = xh + (size_t)(n * IH + oh0) * (IW * CI);

  // initial stage: input rows 0,1,2 -> slots 0,1,2
  stage_row(xb,                 xs,             wv, lane);
  stage_row(xb + (IW * CI),     xs + ROWER,     wv, lane);
  stage_row(xb + 2 * (IW * CI), xs + 2 * ROWER, wv, lane);

  // per-wave tiles: t = wv + 4j over 28 = 2 rows x 14 col-tiles (7 per wave)
  int cbj[7], boff[7];
  bool rj1[7];
#pragma unroll
  for (int j = 0; j < 7; ++j) {
    int t  = wv + j * 4;          // 0..27
    int rj = t / 14;              // output row offset 0..1
    rj1[j] = (rj != 0);
    cbj[j] = (t % 14) * 16;       // 0..208
    boff[j] = (cbj[j] + m) * 64 + q * 16;   // byte offset within a row, kw=0
  }

  f32x4 acc[28];
#pragma unroll
  for (int i = 0; i < 28; ++i) { f32x4 z = {0.f, 0.f, 0.f, 0.f}; acc[i] = z; }

  const __bf16* wpl = wp + m * CI + q * 8;    // lane base into [tap][f][c]

  __syncthreads();

#pragma unroll
  for (int kh = 0; kh < KS; ++kh) {
    if (kh) {
      __syncthreads();            // recycled-slot readers done + prev staged row landed
      if (kh <= 3)                // stage row kh+2 into its slot (kh+2)%3
        stage_row(xb + (size_t)(kh + 2) * (IW * CI),
                  xs + ((kh + 2) % NSLOT) * ROWER, wv, lane);
    }
    const int b0 = (kh % NSLOT) * ROWBR;        // slot byte base for rj=0 (row kh)
    const int b1 = ((kh + 1) % NSLOT) * ROWBR;  // rj=1 (row kh+1)
    int sbj[7];
#pragma unroll
    for (int j = 0; j < 7; ++j) sbj[j] = (rj1[j] ? b1 : b0) + boff[j];

#pragma unroll
    for (int kw = 0; kw < KS; ++kw) {
      bf16x8 af[4];
#pragma unroll
      for (int ft = 0; ft < 4; ++ft)            // 1KB/wave coalesced, L1/L2-resident
        af[ft] = *(const bf16x8*)(wpl + (size_t)(kh * KS + kw) * (NF * CI) + ft * 16 * CI);
#pragma unroll
      for (int j = 0; j < 7; ++j) {
        bf16x8 bv = *(const bf16x8*)((const char*)xs + sbj[j] + kw * 64);
#pragma unroll
        for (int ft = 0; ft < 4; ++ft)
          acc[j * 4 + ft] =
              __builtin_amdgcn_mfma_f32_16x16x32_bf16(af[ft], bv, acc[j * 4 + ft], 0, 0, 0);
      }
    }
  }

  // epilogue: C/D layout col=lane&15 (pixel), row=q*4+reg (filter within 16)
  float bvv[16];
#pragma unroll
  for (int ft = 0; ft < 4; ++ft)
#pragma unroll
    for (int rg = 0; rg < 4; ++rg)
      bvv[ft * 4 + rg] = bias[ft * 16 + q * 4 + rg];

#pragma unroll
  for (int j = 0; j < 7; ++j) {
    int ow = cbj[j] + m;
    if (ow < OWS) {               // only tile 13 masks (px 220..223)
      int oh = oh0 + (rj1[j] ? 1 : 0);
#pragma unroll
      for (int ft = 0; ft < 4; ++ft)
#pragma unroll
        for (int rg = 0; rg < 4; ++rg) {
          int f = ft * 16 + q * 4 + rg;
          out[(((size_t)n * NF + f) * OHS + oh) * OWS + ow] =
              acc[j * 4 + ft][rg] + bvv[ft * 4 + rg];
        }
    }
  }
}

// ---------------- fallbacks (used only if ws too small) ----
__global__ void repack_w_kernel(const float* __restrict__ w, __bf16* __restrict__ wp) {
  int i = blockIdx.x * 256 + threadIdx.x;
  if (i >= KS * KS * NF * CI) return;
  int c   = i & (CI - 1);
  int f   = (i >> 5) & (NF - 1);
  int tap = i >> 11;
  int kh = tap / KS, kw = tap % KS;
  wp[i] = (__bf16)w[((f * CI + c) * KS + kh) * KS + kw];
}

template <bool USE_WS>
__global__ __launch_bounds__(512, 1)
void conv_main(const float* __restrict__ x, const float* __restrict__ w,
               const __bf16* __restrict__ wp, const float* __restrict__ bias,
               float* __restrict__ out) {
  __shared__ __bf16 xs[XROWS * XCOLS * CP];
  __shared__ __bf16 wsm[NBUFW];

  const int tid  = threadIdx.x;
  const int lane = tid & 63;
  const int wv   = tid >> 6;
  const int m    = lane & 15;
  const int q    = lane >> 4;

  int bid = blockIdx.x;
  int lid = (bid >> 3) + (bid & 7) * 110;
  const int n   = lid / 55;
  const int oh0 = (lid % 55) * 4;

  {
    const float* xn = x + (size_t)n * CI * IH * IW;
    for (int p = tid; p < XROWS * 56 * 8; p += 512) {
      int pc   = p & 7;
      int pg   = p >> 3;
      int pcol = pg % 56;
      int prow = pg / 56;
      int row  = oh0 + prow;
      f32x4 v0 = *(const f32x4*)(xn + ((size_t)(pc * 4 + 0) * IH + row) * IW + pcol * 4);
      f32x4 v1 = *(const f32x4*)(xn + ((size_t)(pc * 4 + 1) * IH + row) * IW + pcol * 4);
      f32x4 v2 = *(const f32x4*)(xn + ((size_t)(pc * 4 + 2) * IH + row) * IW + pcol * 4);
      f32x4 v3 = *(const f32x4*)(xn + ((size_t)(pc * 4 + 3) * IH + row) * IW + pcol * 4);
#pragma unroll
      for (int dcol = 0; dcol < 4; ++dcol) {
        bf16x4 t;
        t[0] = (__bf16)v0[dcol]; t[1] = (__bf16)v1[dcol];
        t[2] = (__bf16)v2[dcol]; t[3] = (__bf16)v3[dcol];
        *(bf16x4*)&xs[(prow * XCOLS + pcol * 4 + dcol) * CP + pc * 4] = t;
      }
    }
    for (int z = tid; z < XROWS * 4 * CP; z += 512) {
      int rr  = z / (4 * CP);
      int rem = z - rr * (4 * CP);
      xs[(rr * XCOLS + 224) * CP + rem] = (__bf16)0.0f;
    }
  }

  if (USE_WS) {
    for (int i = tid; i < NF * CI * KS / 8; i += 512) {
      int c0 = (i & 3) * 8;
      int f  = (i >> 2) & 63;
      int kw = i >> 8;
      bf16x8 v = *(const bf16x8*)(wp + ((size_t)(0 * KS + kw) * NF + f) * CI + c0);
      *(bf16x8*)&wsm[(kw * NF + f) * WPD + c0] = v;
    }
  } else {
    for (int i = tid; i < KS * NF * CI; i += 512) {
      int c  = i & 31;
      int f  = (i >> 5) & 63;
      int kw = i >> 11;
      wsm[(kw * NF + f) * WPD + c] = (__bf16)w[((f * CI + c) * KS + 0) * KS + kw];
    }
  }
  __syncthreads();

  int rj[7], cbj[7], xoff[7];
#pragma unroll
  for (int j = 0; j < 7; ++j) {
    int t   = wv + j * 8;
    rj[j]   = t / 14;
    cbj[j]  = (t % 14) * 16;
    xoff[j] = (rj[j] * XCOLS + cbj[j] + m) * CP + q * 8;
  }

  f32x4 acc[28];
#pragma unroll
  for (int i = 0; i < 28; ++i) { f32x4 z = {0.f, 0.f, 0.f, 0.f}; acc[i] = z; }

  for (int kh = 0; kh < KS; ++kh) {
    bf16x8 pw[3];
    if (USE_WS && kh < KS - 1) {
#pragma unroll
      for (int it = 0; it < 3; ++it) {
        int e = it * 512 + tid;
        if (e < 1280) {
          int c0 = (e & 3) * 8;
          int f  = (e >> 2) & 63;
          int kw = e >> 8;
          pw[it] = *(const bf16x8*)(wp + ((size_t)((kh + 1) * KS + kw) * NF + f) * CI + c0);
        }
      }
    }

#pragma unroll
    for (int kw = 0; kw < KS; ++kw) {
      bf16x8 af[4];
#pragma unroll
      for (int ft = 0; ft < 4; ++ft)
        af[ft] = *(const bf16x8*)&wsm[(kw * NF + ft * 16 + m) * WPD + q * 8];
#pragma unroll
      for (int j = 0; j < 7; ++j) {
        const __bf16* bp = &xs[xoff[j] + (kh * XCOLS + kw) * CP];
        bf16x4 lo = *(const bf16x4*)bp;
        bf16x4 hi = *(const bf16x4*)(bp + 4);
        bf16x8 bv8 = __builtin_shufflevector(lo, hi, 0, 1, 2, 3, 4, 5, 6, 7);
#pragma unroll
        for (int ft = 0; ft < 4; ++ft)
          acc[j * 4 + ft] =
              __builtin_amdgcn_mfma_f32_16x16x32_bf16(af[ft], bv8, acc[j * 4 + ft], 0, 0, 0);
      }
    }

    if (kh < KS - 1) {
      __syncthreads();
      if (USE_WS) {
#pragma unroll
        for (int it = 0; it < 3; ++it) {
          int e = it * 512 + tid;
          if (e < 1280) {
            int c0 = (e & 3) * 8;
            int f  = (e >> 2) & 63;
            int kw = e >> 8;
            *(bf16x8*)&wsm[(kw * NF + f) * WPD + c0] = pw[it];
          }
        }
      } else {
        for (int i = tid; i < KS * NF * CI; i += 512) {
          int c  = i & 31;
          int f  = (i >> 5) & 63;
          int kw = i >> 11;
          wsm[(kw * NF + f) * WPD + c] =
              (__bf16)w[((f * CI + c) * KS + (kh + 1)) * KS + kw];
        }
      }
      __syncthreads();
    }
  }

  float bvv[16];
#pragma unroll
  for (int ft = 0; ft < 4; ++ft)
#pragma unroll
    for (int rg = 0; rg < 4; ++rg)
      bvv[ft * 4 + rg] = bias[ft * 16 + q * 4 + rg];

#pragma unroll
  for (int j = 0; j < 7; ++j) {
    int ow = cbj[j] + m;
    if (ow < OWS) {
      int oh = oh0 + rj[j];
#pragma unroll
      for (int ft = 0; ft < 4; ++ft) {
#pragma unroll
        for (int rg = 0; rg < 4; ++rg) {
          int f = ft * 16 + q * 4 + rg;
          out[(((size_t)n * NF + f) * OHS + oh) * OWS + ow] = acc[j * 4 + ft][rg] + bvv[ft * 4 + rg];
        }
      }
    }
  }
}

extern "C" void kernel_launch(void* const* d_in, const int* in_sizes, int n_in,
                              void* d_out, int out_size, void* d_ws, size_t ws_size,
                              hipStream_t stream) {
  const float* x    = (const float*)d_in[0];
  const float* w    = (const float*)d_in[1];
  const float* bias = (const float*)d_in[2];
  float* out = (float*)d_out;

  const int    NW = KS * KS * NF * CI;                              // 51200
  const size_t WB = (size_t)NW * sizeof(__bf16);                    // 102400 B
  const size_t XB = (size_t)16 * IH * IW * CI * sizeof(__bf16);     // 51,380,224 B

  if (ws_size >= XB + WB) {
    // fast path: NHWC bf16 x first, repacked weights after it (tail spill
    // reads from the last staged row land in wp: finite, store-masked)
    __bf16* xhp = (__bf16*)d_ws;
    __bf16* wp  = (__bf16*)((char*)d_ws + XB);
    prep_kernel<<<(16 * IH * IW * 4) / 256, 256, 0, stream>>>(x, w, xhp, wp);
    conv_ring2<<<1760, 256, 0, stream>>>(xhp, wp, bias, out);
  } else if (ws_size >= WB) {
    __bf16* wp = (__bf16*)d_ws;
    repack_w_kernel<<<(NW + 255) / 256, 256, 0, stream>>>(w, wp);
    conv_main<true><<<880, 512, 0, stream>>>(x, w, wp, bias, out);
  } else {
    conv_main<false><<<880, 512, 0, stream>>>(x, w, nullptr, bias, out);
  }
}